// Round 9
// baseline (6724.806 us; speedup 1.0000x reference)
//
#include <hip/hip_runtime.h>
#include <stdint.h>
#include <stddef.h>

// Problem constants (ESN_58317065945127)
#define B_    128
#define T_    2048
#define D_    128
#define H_    1024
#define O_    32
#define LAST_ 20

// Partition: 8 batch-blocks x 16 col-blocks = 128 WGs of 256 threads.
#define NB_   8
#define NC_   16
#define RING_ 4
#define TWARM_ 8      // steps [1,TWARM): ring B (sc1) exchange; >=TWARM: ring A only

typedef __bf16 bf16x8 __attribute__((ext_vector_type(8)));
typedef __bf16 bf16x4 __attribute__((ext_vector_type(4)));
typedef float  f32x4  __attribute__((ext_vector_type(4)));
typedef unsigned int u32x4 __attribute__((ext_vector_type(4)));

union Pack8  { unsigned long long u;    bf16x4 v; };
union Pack16 { unsigned long long u[2]; u32x4 d; bf16x8 v; };

__device__ __forceinline__ float tanh_fast(float s) {
    float a = fminf(fmaxf(s, -12.0f), 12.0f);
    float e = __expf(2.0f * a);
    return (e - 1.0f) / (e + 1.0f);
}

// R13: K-SPLIT MFMA — KILL THE LDS FAN-OUT.
//
// R12 post-mortem: heaters resident (occupancy doubled) yet dur unchanged
// -> clock theory dead. Fresh audit found the invariant cost none of the
// exchange rewrites touched: SQ_LDS_BANK_CONFLICT = 1.342e8 in EVERY round
// (512 cy/WG/step) on top of ~1900cy/step of serialized LDS pipe work —
// all 4 waves of a WG read the SAME 32KB h-tile from LDS (128 b128-reads +
// 32 staged writes per CU per step) + a barrier. ~1us/step, mechanism-
// invariant. That is the pacer candidate the evidence table allows.
//
// R13 restructures the recurrent GEMM: each wave now takes a K-SLICE of
// 256 (8KB of h — exactly its old staging quarter) for ALL 64 of the WG's
// output cols, computing partials accp[nb] (nb=0..3 col-blocks); a small
// conflict-free (+1 pad) double-buffered LDS reduction combines the 4
// waves' partials. Steady state fetches the K-slice DIRECTLY from ring A
// into MFMA B-fragments (8 dwordx4 sc0 loads/lane — same count as the old
// staging loads): no h staging, no 128 LDS reads, no staging barrier.
//
// Gating unchanged: sentinel poll covers ALL 64 producer waves (drift <=1,
// RING=4 safe), per-word lap tags gate acceptance, budget/deadline rescue.
// Warmup/no-vote keeps the proven ring-B full-poll + LDS stage, reading
// only the wave's K-slice from LDS. Math identical mod fp32 add order.
__global__ __launch_bounds__(256, 1) void esn_persist(
    const float* __restrict__ x, const float* __restrict__ w_in,
    const float* __restrict__ w_r, __bf16* __restrict__ h_exA,
    __bf16* __restrict__ h_exB, float* __restrict__ hs,
    int* __restrict__ flags)
{
    __shared__ bf16x8 ls[2][16][128];   // warmup h staging (64 KiB)
    __shared__ f32x4  lsr[2][4][64][5]; // partial-sum reduction, +1 pad (40 KiB)

    const int wg  = (int)blockIdx.x;
    const int bb  = wg & (NB_ - 1);  // cohort id (batch block)
    const int cb  = wg >> 3;
    const int tid = (int)threadIdx.x;
    const int wv  = tid >> 6;
    const int ln  = tid & 63;
    const int nn  = ln & 15;   // batch index within tile
    const int q   = ln >> 4;   // quad
    const int b0  = bb * 16;
    const int n0  = cb * 64 + wv * 16;   // this wave's output col block (nb == wv)

    // Spin deadline ~3s (anti-hang only; tags make acceptance safe).
    const unsigned long long tdead =
        __builtin_amdgcn_s_memrealtime() + 300000000ull;

    // ---- XCD detection, publish leg ----
    int xcc;
    asm volatile("s_getreg_b32 %0, hwreg(HW_REG_XCC_ID)" : "=s"(xcc));
    const int mytag = 0x5A5A0000 | (xcc & 0xFF);
    if (tid == 0)
        __hip_atomic_store(flags + wg, mytag, __ATOMIC_RELAXED,
                           __HIP_MEMORY_SCOPE_AGENT);

    // ---- one-time: weight fragments (K-split layout) ----
    bf16x8 win[4];                       // w_in cols (own block), K=128 -> 4 chunks
    #pragma unroll
    for (int c = 0; c < 4; ++c) {
        bf16x8 f;
        #pragma unroll
        for (int j = 0; j < 8; ++j)
            f[j] = (__bf16)w_in[(size_t)(c * 32 + q * 8 + j) * H_ + (n0 + nn)];
        win[c] = f;
    }
    // wrS[kcl][nb]: rows (wv*8+kcl)*32 + q*8 + j, col cb*64 + nb*16 + nn
    bf16x8 wrS[8][4];                    // 128 VGPRs (same budget as before)
    #pragma unroll
    for (int kcl = 0; kcl < 8; ++kcl) {
        #pragma unroll
        for (int nb = 0; nb < 4; ++nb) {
            bf16x8 f;
            #pragma unroll
            for (int j = 0; j < 8; ++j)
                f[j] = (__bf16)w_r[(size_t)((wv * 8 + kcl) * 32 + q * 8 + j) * H_
                                   + (cb * 64 + nb * 16 + nn)];
            wrS[kcl][nb] = f;
        }
    }

    // ---- XCD detection, collect leg: unanimous vote enables ring A ----
    bool votefast;
    {
        int alleq = 0;
        for (;;) {
            int seen = 1; alleq = 1;
            #pragma unroll
            for (int k = 0; k < NC_; ++k) {
                int v = __hip_atomic_load(flags + (bb + 8 * k), __ATOMIC_RELAXED,
                                          __HIP_MEMORY_SCOPE_AGENT);
                seen  &= (int)((v & 0xFFFF0000) == 0x5A5A0000);
                alleq &= (int)(v == mytag);
            }
            if (seen) break;
            __builtin_amdgcn_s_sleep(8);
            if (__builtin_amdgcn_s_memrealtime() > tdead) { alleq = 0; break; }
        }
        votefast = (alleq != 0);
    }

    const float* xrow = x + (size_t)(b0 + nn) * T_ * D_ + q * 8;  // x[b][t][k]
    const size_t hrow = (size_t)(b0 + nn) * H_;

    // sentinel: row 15, col (ln>>2)*64 + (ln&3)*16 + 12 — the q=3 word of
    // producer wave (cb'=ln>>2, wv'=ln&3), written by its lane 63.
    const int scol = (ln >> 2) * 64 + (ln & 3) * 16 + 12;

    // x prefetch (distance 1)
    f32x4 xn[8];
    bf16x8 xf[4];
    {
        #pragma unroll
        for (int c = 0; c < 4; ++c) {
            xn[2 * c]     = *(const f32x4*)(xrow + c * 32);
            xn[2 * c + 1] = *(const f32x4*)(xrow + c * 32 + 4);
        }
        #pragma unroll
        for (int c = 0; c < 4; ++c) {
            bf16x8 f;
            #pragma unroll
            for (int j = 0; j < 4; ++j) {
                f[j]     = (__bf16)xn[2 * c][j];
                f[j + 4] = (__bf16)xn[2 * c + 1][j];
            }
            xf[c] = f;
        }
    }

    float hm0 = 0.f, hm1 = 0.f, hm2 = 0.f, hm3 = 0.f;  // fp32 master h

    for (int t = 0; t < T_; ++t) {
        // issue x loads for t+1 NOW (fly during poll + compute)
        {
            const int tn = (t + 1 < T_) ? t + 1 : T_ - 1;
            const float* xp = xrow + (size_t)tn * D_;
            #pragma unroll
            for (int c = 0; c < 4; ++c) {
                xn[2 * c]     = *(const f32x4*)(xp + c * 32);
                xn[2 * c + 1] = *(const f32x4*)(xp + c * 32 + 4);
            }
        }

        // x-projection (own col block), 2 chains — retires while polling
        f32x4 xa0 = {0.f, 0.f, 0.f, 0.f}, xa1 = {0.f, 0.f, 0.f, 0.f};
        xa0 = __builtin_amdgcn_mfma_f32_16x16x32_bf16(win[0], xf[0], xa0, 0, 0, 0);
        xa1 = __builtin_amdgcn_mfma_f32_16x16x32_bf16(win[1], xf[1], xa1, 0, 0, 0);
        xa0 = __builtin_amdgcn_mfma_f32_16x16x32_bf16(win[2], xf[2], xa0, 0, 0, 0);
        xa1 = __builtin_amdgcn_mfma_f32_16x16x32_bf16(win[3], xf[3], xa1, 0, 0, 0);

        // recurrent partials: this wave's K-slice x all 4 col blocks
        f32x4 accp[4];
        #pragma unroll
        for (int nb = 0; nb < 4; ++nb) accp[nb] = (f32x4){0.f, 0.f, 0.f, 0.f};

        if (t > 0) {
            const unsigned long long want1 =
                (unsigned long long)((((t - 1) >> 2) & 1) ^ 1) * 0x100000001ull;
            const int sb = (t - 1) & 1;
            const size_t slotoff =
                (size_t)((t - 1) & (RING_ - 1)) * (B_ * H_) + (size_t)b0 * H_;

            if (votefast && t >= TWARM_) {
                // ---- phase 1: sentinel poll on ring A (full-h gating) ----
                {
                    const unsigned long long* sp = (const unsigned long long*)
                        (h_exA + slotoff + 15 * H_ + scol);
                    int spins = 0;
                    for (;;) {
                        unsigned long long s;
                        asm volatile("global_load_dwordx2 %0, %1, off sc0 nt"
                                     : "=v"(s) : "v"(sp) : "memory");
                        asm volatile("s_waitcnt vmcnt(0)" : "+v"(s) :: "memory");
                        if (__all(((s ^ want1) & 0x100000001ull) == 0)) break;
                        if (((++spins) & 255) == 0 &&
                            __builtin_amdgcn_s_memrealtime() > tdead) break;
                    }
                }
                // ---- phase 2: direct K-slice fetch -> MFMA B-fragments ----
                // lane (nn,q), frag kcl: h[row nn][cols (wv*8+kcl)*32 + q*8 ..+7]
                Pack16 pk[8];
                const __bf16* fb = h_exA + slotoff + (size_t)nn * H_
                                   + (size_t)(wv * 256) + q * 8;
                int spins = 0;
                for (;;) {
                    #pragma unroll
                    for (int i = 0; i < 8; ++i) {
                        const __bf16* gp = fb + (size_t)(i * 32);
                        asm volatile("global_load_dwordx4 %0, %1, off sc0 nt"
                                     : "=v"(pk[i].d) : "v"(gp) : "memory");
                    }
                    asm volatile("s_waitcnt vmcnt(0)"
                                 : "+v"(pk[0].d), "+v"(pk[1].d), "+v"(pk[2].d),
                                   "+v"(pk[3].d), "+v"(pk[4].d), "+v"(pk[5].d),
                                   "+v"(pk[6].d), "+v"(pk[7].d) :: "memory");
                    __builtin_amdgcn_sched_barrier(0);
                    unsigned ok = 1u;
                    #pragma unroll
                    for (int i = 0; i < 8; ++i) {
                        ok &= (unsigned)(((pk[i].u[0] ^ want1) & 0x100000001ull) == 0);
                        ok &= (unsigned)(((pk[i].u[1] ^ want1) & 0x100000001ull) == 0);
                    }
                    if (__all(ok != 0u)) break;
                    if (((++spins) & 63) == 0 &&
                        __builtin_amdgcn_s_memrealtime() > tdead) break;  // anti-hang
                }
                #pragma unroll
                for (int kcl = 0; kcl < 8; ++kcl) {
                    const bf16x8 fr = pk[kcl].v;
                    accp[0] = __builtin_amdgcn_mfma_f32_16x16x32_bf16(wrS[kcl][0], fr, accp[0], 0, 0, 0);
                    accp[1] = __builtin_amdgcn_mfma_f32_16x16x32_bf16(wrS[kcl][1], fr, accp[1], 0, 0, 0);
                    accp[2] = __builtin_amdgcn_mfma_f32_16x16x32_bf16(wrS[kcl][2], fr, accp[2], 0, 0, 0);
                    accp[3] = __builtin_amdgcn_mfma_f32_16x16x32_bf16(wrS[kcl][3], fr, accp[3], 0, 0, 0);
                }
            } else {
                // ---- warmup / no-vote: ring B full poll + LDS stage (R6) ----
                Pack16 pk[8];
                const __bf16* hbase = h_exB + slotoff;
                int spins = 0;
                for (;;) {
                    #pragma unroll
                    for (int i = 0; i < 8; ++i) {
                        const int p = wv * 512 + i * 64 + ln;
                        const unsigned long long* gp = (const unsigned long long*)
                            (hbase + (size_t)(p >> 7) * H_ + (p & 127) * 8);
                        pk[i].u[0] = __hip_atomic_load(gp, __ATOMIC_RELAXED,
                                                       __HIP_MEMORY_SCOPE_AGENT);
                        pk[i].u[1] = __hip_atomic_load(gp + 1, __ATOMIC_RELAXED,
                                                       __HIP_MEMORY_SCOPE_AGENT);
                    }
                    unsigned ok = 1u;
                    #pragma unroll
                    for (int i = 0; i < 8; ++i) {
                        ok &= (unsigned)(((pk[i].u[0] ^ want1) & 0x100000001ull) == 0);
                        ok &= (unsigned)(((pk[i].u[1] ^ want1) & 0x100000001ull) == 0);
                    }
                    if (__all(ok != 0u)) break;
                    __builtin_amdgcn_s_sleep(1);
                    if (((++spins) & 63) == 0 &&
                        __builtin_amdgcn_s_memrealtime() > tdead) break;  // anti-hang
                }
                #pragma unroll
                for (int i = 0; i < 8; ++i) {
                    const int p = wv * 512 + i * 64 + ln;
                    const int r = p >> 7, ch = p & 127;
                    ls[sb][r][ch ^ (r & 7)] = pk[i].v;   // XOR swizzle
                }
                __syncthreads();
                // K-slice MFMAs from LDS (8 reads instead of 32)
                #pragma unroll
                for (int kcl = 0; kcl < 8; ++kcl) {
                    const int kg = wv * 8 + kcl;
                    const bf16x8 fr = ls[sb][nn][(kg * 4 + q) ^ (nn & 7)];
                    accp[0] = __builtin_amdgcn_mfma_f32_16x16x32_bf16(wrS[kcl][0], fr, accp[0], 0, 0, 0);
                    accp[1] = __builtin_amdgcn_mfma_f32_16x16x32_bf16(wrS[kcl][1], fr, accp[1], 0, 0, 0);
                    accp[2] = __builtin_amdgcn_mfma_f32_16x16x32_bf16(wrS[kcl][2], fr, accp[2], 0, 0, 0);
                    accp[3] = __builtin_amdgcn_mfma_f32_16x16x32_bf16(wrS[kcl][3], fr, accp[3], 0, 0, 0);
                }
            }
        }

        // ---- cross-wave reduction of K-partials (conflict-free, dbuf) ----
        const int rb = t & 1;
        #pragma unroll
        for (int nb = 0; nb < 4; ++nb)
            lsr[rb][wv][ln][nb] = accp[nb];
        __syncthreads();
        const f32x4 red = (lsr[rb][0][ln][wv] + lsr[rb][1][ln][wv])
                        + (lsr[rb][2][ln][wv] + lsr[rb][3][ln][wv]);

        const f32x4 val = (xa0 + xa1) + red;
        const float th0 = tanh_fast(val[0]);
        const float th1 = tanh_fast(val[1]);
        const float th2 = tanh_fast(val[2]);
        const float th3 = tanh_fast(val[3]);
        if (t == 0) {           // reference: h = tanh(xw[:,0]), no leak at t=0
            hm0 = th0; hm1 = th1; hm2 = th2; hm3 = th3;
        } else {                // h = 0.1*h + 0.9*tanh(.)
            hm0 = 0.1f * hm0 + 0.9f * th0;
            hm1 = 0.1f * hm1 + 0.9f * th1;
            hm2 = 0.1f * hm2 + 0.9f * th2;
            hm3 = 0.1f * hm3 + 0.9f * th3;
        }

        // publish 8B slice, lap tag in bit 0 of BOTH dwords — fire and forget.
        {
            Pack8 p;
            p.v = (bf16x4){(__bf16)hm0, (__bf16)hm1, (__bf16)hm2, (__bf16)hm3};
            const unsigned long long tg =
                (unsigned long long)(((t >> 2) & 1) ^ 1) * 0x100000001ull;
            p.u = (p.u & ~0x100000001ull) | tg;
            const size_t poff = (size_t)(t & (RING_ - 1)) * (B_ * H_)
                                + hrow + n0 + q * 4;
            if (votefast) {
                unsigned long long* opA = (unsigned long long*)(h_exA + poff);
                asm volatile("global_store_dwordx2 %0, %1, off sc0"
                             :: "v"(opA), "v"(p.u) : "memory");
                if (t < TWARM_) {
                    unsigned long long* opB = (unsigned long long*)(h_exB + poff);
                    __hip_atomic_store(opB, p.u, __ATOMIC_RELAXED,
                                       __HIP_MEMORY_SCOPE_AGENT);
                }
            } else {
                unsigned long long* opB = (unsigned long long*)(h_exB + poff);
                __hip_atomic_store(opB, p.u, __ATOMIC_RELAXED,
                                   __HIP_MEMORY_SCOPE_AGENT);
            }
        }

        // off the critical path: tail collection + x bf16 conversion for t+1
        if (t >= T_ - LAST_) {
            f32x4* sp = (f32x4*)(hs + (size_t)(t - (T_ - LAST_)) * (B_ * H_)
                                    + hrow + n0 + q * 4);
            *sp = (f32x4){hm0, hm1, hm2, hm3};
        }
        #pragma unroll
        for (int c = 0; c < 4; ++c) {
            bf16x8 f;
            #pragma unroll
            for (int j = 0; j < 4; ++j) {
                f[j]     = (__bf16)xn[2 * c][j];
                f[j + 4] = (__bf16)xn[2 * c + 1][j];
            }
            xf[c] = f;
        }
    }
}

// Readout: out[b,:] = cat(hs)[b,:] @ W + bias.  One block per batch row.
__global__ __launch_bounds__(256) void esn_out(
    const float* __restrict__ hs, const float* __restrict__ Wm,
    const float* __restrict__ bias, float* __restrict__ out)
{
    const int b   = (int)blockIdx.x;
    const int tid = (int)threadIdx.x;
    float acc[O_];
    #pragma unroll
    for (int o = 0; o < O_; ++o) acc[o] = 0.f;

    for (int k = tid; k < LAST_ * H_; k += 256) {
        // cat order: k = t'*H + c  <->  hs[t'][b][c]
        const float hv = hs[(size_t)(k >> 10) * (B_ * H_) + (size_t)b * H_ + (k & (H_ - 1))];
        const f32x4* wp = (const f32x4*)(Wm + (size_t)k * O_);
        #pragma unroll
        for (int v = 0; v < 8; ++v) {
            f32x4 w4 = wp[v];
            acc[4 * v + 0] = fmaf(hv, w4[0], acc[4 * v + 0]);
            acc[4 * v + 1] = fmaf(hv, w4[1], acc[4 * v + 1]);
            acc[4 * v + 2] = fmaf(hv, w4[2], acc[4 * v + 2]);
            acc[4 * v + 3] = fmaf(hv, w4[3], acc[4 * v + 3]);
        }
    }

    __shared__ float red[256][O_ + 1];  // +1 pad: conflict-free column sums
    #pragma unroll
    for (int o = 0; o < O_; ++o) red[tid][o] = acc[o];
    __syncthreads();
    if (tid < O_) {
        float s = bias[tid];
        for (int i = 0; i < 256; ++i) s += red[i][tid];
        out[(size_t)b * O_ + tid] = s;
    }
}

extern "C" void kernel_launch(void* const* d_in, const int* in_sizes, int n_in,
                              void* d_out, int out_size, void* d_ws, size_t ws_size,
                              hipStream_t stream)
{
    const float* x    = (const float*)d_in[0];  // [128,2048,128]
    const float* w_in = (const float*)d_in[1];  // [128,1024]
    const float* w_r  = (const float*)d_in[2];  // [1024,1024]
    const float* Wm   = (const float*)d_in[3];  // [20480,32]
    const float* bias = (const float*)d_in[4];  // [32]
    float* out        = (float*)d_out;          // [128,32]

    const size_t flag_bytes = 4096;                                      // 128 ints used
    const size_t ring_bytes = (size_t)RING_ * B_ * H_ * sizeof(__bf16);  // 1 MiB each
    const size_t hs_bytes   = (size_t)LAST_ * B_ * H_ * sizeof(float);   // 10 MiB
    if (ws_size < flag_bytes + 2 * ring_bytes + hs_bytes) return;  // fail loud

    int*    flags = (int*)d_ws;
    __bf16* h_exA = (__bf16*)((char*)d_ws + flag_bytes);
    __bf16* h_exB = (__bf16*)((char*)d_ws + flag_bytes + ring_bytes);
    float*  hs    = (float*)((char*)d_ws + flag_bytes + 2 * ring_bytes);

    // flags = 0 (no XCD votes yet; 0 fails the 0x5A5A pattern check).
    // Rings = 0xAA: tag bit 0 = 0 = stale for t=0 (t=0 publishes tag 1).
    hipMemsetAsync(flags, 0x00, flag_bytes, stream);
    hipMemsetAsync(h_exA, 0xAA, 2 * ring_bytes, stream);

    hipLaunchKernelGGL(esn_persist, dim3(NB_ * NC_), dim3(256), 0, stream,
                       x, w_in, w_r, h_exA, h_exB, hs, flags);
    hipLaunchKernelGGL(esn_out, dim3(B_), dim3(256), 0, stream,
                       hs, Wm, bias, out);
}